// Round 2
// baseline (1705.276 us; speedup 1.0000x reference)
//
#include <hip/hip_runtime.h>

// Problem constants (from reference)
#define kN  100000
#define kE  1600000
#define kNW 512
#define kH  128
#define kL  3
#define kG  256
#define kNEG 0.2f
#define kEPS 1e-5f

static __device__ __forceinline__ float lrelu(float v) { return v >= 0.f ? v : kNEG * v; }

// ---------------- CSR build ----------------
__global__ void count_deg(const int* __restrict__ ei, int* __restrict__ deg, int E) {
    int e = blockIdx.x * 256 + threadIdx.x;
    if (e < E) atomicAdd(&deg[ei[E + e]], 1);
}

// scan pass 1: per-block (1024 elems) sums
__global__ void scan1(const int* __restrict__ deg, int* __restrict__ bsums, int n) {
    __shared__ int sdata[256];
    int b = blockIdx.x, t = threadIdx.x;
    int base = b * 1024 + t * 4;
    int s = 0;
#pragma unroll
    for (int j = 0; j < 4; j++) { int i = base + j; s += (i < n) ? deg[i] : 0; }
    sdata[t] = s; __syncthreads();
    for (int st = 128; st > 0; st >>= 1) { if (t < st) sdata[t] += sdata[t + st]; __syncthreads(); }
    if (t == 0) bsums[b] = sdata[0];
}

// scan pass 2: exclusive-scan the (<=128) block sums with one 128-thread block
__global__ void scan2(int* __restrict__ bsums, int nb, int* __restrict__ row_ptr_last) {
    __shared__ int lds[128];
    int t = threadIdx.x;
    int v = (t < nb) ? bsums[t] : 0;
    lds[t] = v; __syncthreads();
    for (int st = 1; st < 128; st <<= 1) {
        int x = 0;
        if (t >= st) x = lds[t - st];
        __syncthreads();
        if (t >= st) lds[t] += x;
        __syncthreads();
    }
    if (t < nb) bsums[t] = lds[t] - v;          // exclusive
    if (t == nb - 1) row_ptr_last[0] = lds[t];  // total
}

__global__ void scan3(const int* __restrict__ deg, const int* __restrict__ bsums,
                      int* __restrict__ row_ptr, int* __restrict__ cursor, int n) {
    __shared__ int lds[256];
    int b = blockIdx.x, t = threadIdx.x;
    int base = b * 1024 + t * 4;
    int v[4]; int s = 0;
#pragma unroll
    for (int j = 0; j < 4; j++) { int i = base + j; v[j] = (i < n) ? deg[i] : 0; s += v[j]; }
    lds[t] = s; __syncthreads();
    for (int st = 1; st < 256; st <<= 1) {
        int x = 0;
        if (t >= st) x = lds[t - st];
        __syncthreads();
        if (t >= st) lds[t] += x;
        __syncthreads();
    }
    int excl = (t == 0) ? 0 : lds[t - 1];
    excl += bsums[b];
    int run = excl;
#pragma unroll
    for (int j = 0; j < 4; j++) {
        int i = base + j;
        if (i < n) { row_ptr[i] = run; cursor[i] = run; run += v[j]; }
    }
}

__global__ void fill_csr(const int* __restrict__ ei, int* __restrict__ cursor,
                         int* __restrict__ col_src, int E) {
    int e = blockIdx.x * 256 + threadIdx.x;
    if (e < E) {
        int s = ei[e], d = ei[E + e];
        int p = atomicAdd(&cursor[d], 1);
        col_src[p] = s;
    }
}

// ---------------- GEMM: C[M,128] = A[M,K] @ B[K,128] (+bias,relu) ----------------
// BM=128, BN=128, BK=32, 256 threads, thread tile 8x8 (cols split {tx*4, 64+tx*4}
// to keep the Bs fragment read 2-way-max on banks; contiguous tx*8 would be 4-way).
__global__ __launch_bounds__(256) void gemm128(const float* __restrict__ A,
                                               const float* __restrict__ B,
                                               float* __restrict__ C, int M, int K,
                                               const float* __restrict__ bias, int do_relu) {
    __shared__ float As[32][132];  // [k][row]; 132*4=528B rows keep float4 alignment
    __shared__ float Bs[32][128];  // [k][col]
    int tid = threadIdx.x;
    int bm = blockIdx.x * 128;
    int ty = tid >> 4;   // 0..15 -> rows ty*8..+7
    int tx = tid & 15;   // 0..15 -> cols tx*4..+3 and 64+tx*4..+3
    float acc[8][8];
#pragma unroll
    for (int i = 0; i < 8; i++)
#pragma unroll
        for (int j = 0; j < 8; j++) acc[i][j] = 0.f;

    for (int k0 = 0; k0 < K; k0 += 32) {
        // A tile: 128x32 floats = 1024 float4, 4 per thread, transposed into As
#pragma unroll
        for (int l = 0; l < 4; l++) {
            int f = tid + l * 256;
            int r = f >> 3;        // 0..127
            int c4 = f & 7;        // 0..7
            int gr = bm + r;
            float4 v = make_float4(0.f, 0.f, 0.f, 0.f);
            if (gr < M) v = *(const float4*)(A + (size_t)gr * K + k0 + c4 * 4);
            As[c4 * 4 + 0][r] = v.x;
            As[c4 * 4 + 1][r] = v.y;
            As[c4 * 4 + 2][r] = v.z;
            As[c4 * 4 + 3][r] = v.w;
        }
        // B tile: 32x128 floats = 1024 float4, 4 per thread
#pragma unroll
        for (int l = 0; l < 4; l++) {
            int f = tid + l * 256;
            int r = f >> 5;        // 0..31
            int c4 = f & 31;       // 0..31
            *(float4*)&Bs[r][c4 * 4] = *(const float4*)(B + (size_t)(k0 + r) * 128 + c4 * 4);
        }
        __syncthreads();
#pragma unroll
        for (int kk = 0; kk < 32; kk++) {
            float4 a0 = *(float4*)&As[kk][ty * 8];
            float4 a1 = *(float4*)&As[kk][ty * 8 + 4];
            float4 b0 = *(float4*)&Bs[kk][tx * 4];
            float4 b1 = *(float4*)&Bs[kk][64 + tx * 4];
            float aa[8] = {a0.x, a0.y, a0.z, a0.w, a1.x, a1.y, a1.z, a1.w};
            float bb[8] = {b0.x, b0.y, b0.z, b0.w, b1.x, b1.y, b1.z, b1.w};
#pragma unroll
            for (int i = 0; i < 8; i++)
#pragma unroll
                for (int j = 0; j < 8; j++) acc[i][j] += aa[i] * bb[j];
        }
        __syncthreads();
    }
#pragma unroll
    for (int i = 0; i < 8; i++) {
        int gr = bm + ty * 8 + i;
        if (gr >= M) continue;
#pragma unroll
        for (int half = 0; half < 2; half++) {
            int gc = half * 64 + tx * 4;
            float4 v;
            v.x = acc[i][half * 4 + 0]; v.y = acc[i][half * 4 + 1];
            v.z = acc[i][half * 4 + 2]; v.w = acc[i][half * 4 + 3];
            if (bias) { v.x += bias[gc]; v.y += bias[gc + 1]; v.z += bias[gc + 2]; v.w += bias[gc + 3]; }
            if (do_relu) {
                v.x = fmaxf(v.x, 0.f); v.y = fmaxf(v.y, 0.f);
                v.z = fmaxf(v.z, 0.f); v.w = fmaxf(v.w, 0.f);
            }
            *(float4*)(C + (size_t)gr * 128 + gc) = v;
        }
    }
}

// ---------------- per-node attention dots: a_s = h.att_src, a_d = h.att_dst --------
__global__ void att_dots(const float* __restrict__ h, const float* __restrict__ ws_,
                         const float* __restrict__ wd_, float* __restrict__ a_s,
                         float* __restrict__ a_d, int n) {
    int v = blockIdx.x * 4 + (threadIdx.x >> 6);
    int lane = threadIdx.x & 63;
    if (v >= n) return;
    float2 hx = ((const float2*)(h + (size_t)v * 128))[lane];
    float2 ws = ((const float2*)ws_)[lane];
    float2 wd = ((const float2*)wd_)[lane];
    float ps = hx.x * ws.x + hx.y * ws.y;
    float pd = hx.x * wd.x + hx.y * wd.y;
#pragma unroll
    for (int off = 32; off; off >>= 1) {
        ps += __shfl_xor(ps, off);
        pd += __shfl_xor(pd, off);
    }
    if (lane == 0) { a_s[v] = ps; a_d[v] = pd; }
}

// ---------------- per-node edge softmax (incl. self loop), CSR gather -------------
__global__ void edge_softmax(const int* __restrict__ row_ptr, const int* __restrict__ col_src,
                             const float* __restrict__ a_s, const float* __restrict__ a_d,
                             float* __restrict__ coef, float* __restrict__ coef_self, int n) {
    int v = blockIdx.x * 4 + (threadIdx.x >> 6);
    int lane = threadIdx.x & 63;
    if (v >= n) return;
    int s0 = row_ptr[v], s1 = row_ptr[v + 1];
    float adv = a_d[v];
    float es = lrelu(a_s[v] + adv);
    float mx = es;
    for (int k = s0 + lane; k < s1; k += 64) {
        float e = lrelu(a_s[col_src[k]] + adv);
        coef[k] = e;
        mx = fmaxf(mx, e);
    }
#pragma unroll
    for (int off = 32; off; off >>= 1) mx = fmaxf(mx, __shfl_xor(mx, off));
    float sum = 0.f;
    for (int k = s0 + lane; k < s1; k += 64) {
        float ex = expf(coef[k] - mx);
        coef[k] = ex;
        sum += ex;
    }
    if (lane == 0) sum += expf(es - mx);
#pragma unroll
    for (int off = 32; off; off >>= 1) sum += __shfl_xor(sum, off);
    float inv = 1.f / sum;
    for (int k = s0 + lane; k < s1; k += 64) coef[k] *= inv;
    if (lane == 0) coef_self[v] = expf(es - mx) * inv;
}

// ---------------- aggregation: out[v] = sum_in coef*h[src] + coef_self*h[v] + bias -
__global__ void aggregate(const int* __restrict__ row_ptr, const int* __restrict__ col_src,
                          const float* __restrict__ coef, const float* __restrict__ coef_self,
                          const float* __restrict__ h, const float* __restrict__ bias,
                          float* __restrict__ out, int n) {
    int v = blockIdx.x * 4 + (threadIdx.x >> 6);
    int lane = threadIdx.x & 63;
    if (v >= n) return;
    int s0 = row_ptr[v], s1 = row_ptr[v + 1];
    const float2* h2 = (const float2*)h;
    float cs = coef_self[v];
    float2 hv = h2[(size_t)v * 64 + lane];
    float ax = cs * hv.x, ay = cs * hv.y;
    for (int k = s0; k < s1; k++) {
        int s = col_src[k];        // wave-uniform -> scalar load + broadcast
        float c = coef[k];
        float2 hs = h2[(size_t)s * 64 + lane];
        ax += c * hs.x;
        ay += c * hs.y;
    }
    float2 b = ((const float2*)bias)[lane];
    float2 o; o.x = ax + b.x; o.y = ay + b.y;
    ((float2*)out)[(size_t)v * 64 + lane] = o;
}

// ---------------- batchnorm ----------------
__global__ void bn_stats(const float* __restrict__ x, double* __restrict__ sums, int n) {
    int col = threadIdx.x & 127;
    int half = threadIdx.x >> 7;
    double s = 0.0, q = 0.0;
    for (int r = blockIdx.x * 2 + half; r < n; r += gridDim.x * 2) {
        float v = x[(size_t)r * 128 + col];
        s += v;
        q += (double)v * (double)v;
    }
    __shared__ double ls[256], lq[256];
    ls[threadIdx.x] = s; lq[threadIdx.x] = q;
    __syncthreads();
    if (half == 0) {
        s += ls[threadIdx.x + 128];
        q += lq[threadIdx.x + 128];
        atomicAdd(&sums[col], s);
        atomicAdd(&sums[128 + col], q);
    }
}

__global__ void bn_finalize(const double* __restrict__ sums, const float* __restrict__ gamma,
                            const float* __restrict__ beta, float* __restrict__ coefs, int n) {
    int c = threadIdx.x;
    if (c < 128) {
        double mu = sums[c] / n;
        double var = sums[128 + c] / n - mu * mu;
        double rs = 1.0 / sqrt(var + (double)kEPS);
        float sc = (float)rs * gamma[c];
        coefs[c] = sc;
        coefs[128 + c] = beta[c] - (float)(mu * rs) * gamma[c];
    }
}

__global__ void bn_apply(float* __restrict__ x, const float* __restrict__ coefs, int n) {
    int idx = blockIdx.x * 256 + threadIdx.x;
    if (idx >= n * 32) return;
    float4 v = ((const float4*)x)[idx];
    int c = (idx & 31) * 4;
    v.x = fmaxf(v.x * coefs[c + 0] + coefs[128 + c + 0], 0.f);
    v.y = fmaxf(v.y * coefs[c + 1] + coefs[128 + c + 1], 0.f);
    v.z = fmaxf(v.z * coefs[c + 2] + coefs[128 + c + 2], 0.f);
    v.w = fmaxf(v.w * coefs[c + 3] + coefs[128 + c + 3], 0.f);
    ((float4*)x)[idx] = v;
}

// ---------------- gate scalar: gate[v] = hidden[v] . gw2 + gb2 ----------------
__global__ void gate_dot(const float* __restrict__ hidden, const float* __restrict__ gw2,
                         const float* __restrict__ gb2, float* __restrict__ gate, int n) {
    int v = blockIdx.x * 4 + (threadIdx.x >> 6);
    int lane = threadIdx.x & 63;
    if (v >= n) return;
    float2 hx = ((const float2*)(hidden + (size_t)v * 128))[lane];
    float2 w = ((const float2*)gw2)[lane];
    float p = hx.x * w.x + hx.y * w.y;
#pragma unroll
    for (int off = 32; off; off >>= 1) p += __shfl_xor(p, off);
    if (lane == 0) gate[v] = p + gb2[0];
}

// ---------------- graph boundaries (batch sorted) ----------------
__global__ void graph_bounds(const int* __restrict__ batch, int* __restrict__ gstart, int n, int g) {
    int i = blockIdx.x * 256 + threadIdx.x;
    if (i > g) return;
    int lo = 0, hi = n;
    while (lo < hi) {
        int mid = (lo + hi) >> 1;
        if (batch[mid] < i) lo = mid + 1; else hi = mid;
    }
    gstart[i] = lo;
}

// ---------------- softmax-gated pooling, block per graph (512 thr, 4-way node ILP) -
__global__ __launch_bounds__(512) void pool(const float* __restrict__ x, const float* __restrict__ gate,
                                            const int* __restrict__ gstart, float* __restrict__ pooled) {
    int g = blockIdx.x;
    int t = threadIdx.x;
    int col = t & 127;
    int q = t >> 7;            // 0..3
    int s0 = gstart[g], s1 = gstart[g + 1];
    __shared__ float red[8];
    __shared__ float acc_lds[512];
    // pass 1: max over gate
    float mx = -INFINITY;
    for (int v = s0 + t; v < s1; v += 512) mx = fmaxf(mx, gate[v]);
#pragma unroll
    for (int off = 32; off; off >>= 1) mx = fmaxf(mx, __shfl_xor(mx, off));
    if ((t & 63) == 0) red[t >> 6] = mx;
    __syncthreads();
    mx = fmaxf(fmaxf(fmaxf(red[0], red[1]), fmaxf(red[2], red[3])),
               fmaxf(fmaxf(red[4], red[5]), fmaxf(red[6], red[7])));
    __syncthreads();
    // pass 2: sum of exp
    float sum = 0.f;
    for (int v = s0 + t; v < s1; v += 512) sum += expf(gate[v] - mx);
#pragma unroll
    for (int off = 32; off; off >>= 1) sum += __shfl_xor(sum, off);
    if ((t & 63) == 0) red[t >> 6] = sum;
    __syncthreads();
    sum = red[0] + red[1] + red[2] + red[3] + red[4] + red[5] + red[6] + red[7];
    if (sum == 0.f) sum = 1.f;
    float inv = 1.f / sum;
    // pass 3: weighted feature sum, 4 nodes in flight
    float acc = 0.f;
    for (int v = s0 + q; v < s1; v += 4) {
        float c = expf(gate[v] - mx) * inv;
        acc += x[(size_t)v * 128 + col] * c;
    }
    acc_lds[t] = acc;
    __syncthreads();
    if (q == 0)
        pooled[(size_t)g * 128 + col] = acc_lds[col] + acc_lds[128 + col] +
                                        acc_lds[256 + col] + acc_lds[384 + col];
}

// ---------------- classifier + log_softmax (wave per graph) ----------------
__global__ void classify(const float* __restrict__ pooled, const float* __restrict__ cls_w,
                         const float* __restrict__ cls_b, float* __restrict__ out, int g_) {
    int g = blockIdx.x * 4 + (threadIdx.x >> 6);
    int lane = threadIdx.x & 63;
    if (g >= g_) return;
    float2 p = ((const float2*)(pooled + (size_t)g * 128))[lane];
    float4 w = ((const float4*)cls_w)[lane];  // W(2lane,0),W(2lane,1),W(2lane+1,0),W(2lane+1,1)
    float l0 = p.x * w.x + p.y * w.z;
    float l1 = p.x * w.y + p.y * w.w;
#pragma unroll
    for (int off = 32; off; off >>= 1) {
        l0 += __shfl_xor(l0, off);
        l1 += __shfl_xor(l1, off);
    }
    if (lane == 0) {
        l0 += cls_b[0]; l1 += cls_b[1];
        float m = fmaxf(l0, l1);
        float lse = m + logf(expf(l0 - m) + expf(l1 - m));
        out[g * 2 + 0] = l0 - lse;
        out[g * 2 + 1] = l1 - lse;
    }
}

extern "C" void kernel_launch(void* const* d_in, const int* in_sizes, int n_in,
                              void* d_out, int out_size, void* d_ws, size_t ws_size,
                              hipStream_t stream) {
    const float* x        = (const float*)d_in[0];
    const int*   ei       = (const int*)d_in[1];   // [2][E]
    // d_in[2] edge_attr, d_in[4] edge_emb: dead in reference
    const int*   batch    = (const int*)d_in[3];
    const float* W0       = (const float*)d_in[5];
    const float* W_rest   = (const float*)d_in[6];
    const float* att_src  = (const float*)d_in[7];
    const float* att_dst  = (const float*)d_in[8];
    const float* bias     = (const float*)d_in[9];
    const float* gamma    = (const float*)d_in[10];
    const float* beta     = (const float*)d_in[11];
    const float* gate_w1  = (const float*)d_in[12];
    const float* gate_b1  = (const float*)d_in[13];
    const float* gate_w2  = (const float*)d_in[14];
    const float* gate_b2  = (const float*)d_in[15];
    const float* cls_w    = (const float*)d_in[16];
    const float* cls_b    = (const float*)d_in[17];
    float* out = (float*)d_out;

    char* ws = (char*)d_ws;
    size_t off = 0;
    auto take = [&](size_t bytes) -> void* {
        void* p = ws + off;
        off += (bytes + 255) & ~(size_t)255;
        return p;
    };
    float* h         = (float*)take((size_t)kN * kH * 4);
    float* xa        = (float*)take((size_t)kN * kH * 4);
    float* a_s       = (float*)take((size_t)kN * 4);
    float* a_d       = (float*)take((size_t)kN * 4);
    float* coef_self = (float*)take((size_t)kN * 4);
    int*   deg       = (int*)take((size_t)kN * 4);
    int*   cursor    = (int*)take((size_t)kN * 4);
    int*   row_ptr   = (int*)take((size_t)(kN + 1) * 4);
    int*   col_src   = (int*)take((size_t)kE * 4);
    float* coef_csr  = (float*)take((size_t)kE * 4);
    int*   bsums     = (int*)take(1024 * 4);
    double* bn_sums  = (double*)take(256 * 8);
    float* bn_coefs  = (float*)take(256 * 4);
    float* gate      = (float*)take((size_t)kN * 4);
    int*   gstart    = (int*)take((size_t)(kG + 1) * 4);
    float* pooled    = (float*)take((size_t)kG * kH * 4);
    (void)ws_size; (void)in_sizes; (void)n_in; (void)out_size;

    const int NB = (kN + 1023) / 1024;   // 98 scan blocks (<=128 for scan2)

    // ---- CSR build (per-call; ws is re-poisoned each launch) ----
    hipMemsetAsync(deg, 0, (size_t)kN * 4, stream);
    count_deg<<<(kE + 255) / 256, 256, 0, stream>>>(ei, deg, kE);
    scan1<<<NB, 256, 0, stream>>>(deg, bsums, kN);
    scan2<<<1, 128, 0, stream>>>(bsums, NB, row_ptr + kN);
    scan3<<<NB, 256, 0, stream>>>(deg, bsums, row_ptr, cursor, kN);
    fill_csr<<<(kE + 255) / 256, 256, 0, stream>>>(ei, cursor, col_src, kE);

    // ---- 3 GAT layers ----
    const float* xin = x;
    int K = kNW;
    for (int l = 0; l < kL; l++) {
        const float* W = (l == 0) ? W0 : (W_rest + (size_t)(l - 1) * kH * kH);
        gemm128<<<(kN + 127) / 128, 256, 0, stream>>>(xin, W, h, kN, K, nullptr, 0);
        att_dots<<<(kN + 3) / 4, 256, 0, stream>>>(h, att_src + (size_t)l * kH,
                                                   att_dst + (size_t)l * kH, a_s, a_d, kN);
        edge_softmax<<<(kN + 3) / 4, 256, 0, stream>>>(row_ptr, col_src, a_s, a_d,
                                                       coef_csr, coef_self, kN);
        aggregate<<<(kN + 3) / 4, 256, 0, stream>>>(row_ptr, col_src, coef_csr, coef_self,
                                                    h, bias + (size_t)l * kH, xa, kN);
        hipMemsetAsync(bn_sums, 0, 256 * 8, stream);
        bn_stats<<<1024, 256, 0, stream>>>(xa, bn_sums, kN);
        bn_finalize<<<1, 128, 0, stream>>>(bn_sums, gamma + (size_t)l * kH,
                                           beta + (size_t)l * kH, bn_coefs, kN);
        bn_apply<<<((kN * 32) + 255) / 256, 256, 0, stream>>>(xa, bn_coefs, kN);
        xin = xa;
        K = kH;
    }

    // ---- gate MLP (reuse h as hidden buffer) ----
    gemm128<<<(kN + 127) / 128, 256, 0, stream>>>(xa, gate_w1, h, kN, kH, gate_b1, 1);
    gate_dot<<<(kN + 3) / 4, 256, 0, stream>>>(h, gate_w2, gate_b2, gate, kN);

    // ---- pooling + classifier ----
    graph_bounds<<<2, 256, 0, stream>>>(batch, gstart, kN, kG);
    pool<<<kG, 512, 0, stream>>>(xa, gate, gstart, pooled);
    classify<<<(kG + 3) / 4, 256, 0, stream>>>(pooled, cls_w, cls_b, out, kG);
}

// Round 3
// 1613.137 us; speedup vs baseline: 1.0571x; 1.0571x over previous
//
#include <hip/hip_runtime.h>

// Problem constants (from reference)
#define kN  100000
#define kE  1600000
#define kNW 512
#define kH  128
#define kL  3
#define kG  256
#define kNEG 0.2f
#define kEPS 1e-5f

typedef __attribute__((ext_vector_type(8))) short bf16x8;
typedef __attribute__((ext_vector_type(4))) float f32x4;

static __device__ __forceinline__ float lrelu(float v) { return v >= 0.f ? v : kNEG * v; }

static __device__ __forceinline__ unsigned short bf16rn(float x) {
    unsigned u = __float_as_uint(x);
    return (unsigned short)((u + 0x7FFFu + ((u >> 16) & 1u)) >> 16);
}
static __device__ __forceinline__ float bf16tof(unsigned short h) {
    return __uint_as_float(((unsigned)h) << 16);
}

// ---------------- CSR build ----------------
__global__ void count_deg(const int* __restrict__ ei, int* __restrict__ deg, int E) {
    int e = blockIdx.x * 256 + threadIdx.x;
    if (e < E) atomicAdd(&deg[ei[E + e]], 1);
}

__global__ void scan1(const int* __restrict__ deg, int* __restrict__ bsums, int n) {
    __shared__ int sdata[256];
    int b = blockIdx.x, t = threadIdx.x;
    int base = b * 1024 + t * 4;
    int s = 0;
#pragma unroll
    for (int j = 0; j < 4; j++) { int i = base + j; s += (i < n) ? deg[i] : 0; }
    sdata[t] = s; __syncthreads();
    for (int st = 128; st > 0; st >>= 1) { if (t < st) sdata[t] += sdata[t + st]; __syncthreads(); }
    if (t == 0) bsums[b] = sdata[0];
}

__global__ void scan2(int* __restrict__ bsums, int nb, int* __restrict__ row_ptr_last) {
    __shared__ int lds[128];
    int t = threadIdx.x;
    int v = (t < nb) ? bsums[t] : 0;
    lds[t] = v; __syncthreads();
    for (int st = 1; st < 128; st <<= 1) {
        int x = 0;
        if (t >= st) x = lds[t - st];
        __syncthreads();
        if (t >= st) lds[t] += x;
        __syncthreads();
    }
    if (t < nb) bsums[t] = lds[t] - v;
    if (t == nb - 1) row_ptr_last[0] = lds[t];
}

__global__ void scan3(const int* __restrict__ deg, const int* __restrict__ bsums,
                      int* __restrict__ row_ptr, int* __restrict__ cursor, int n) {
    __shared__ int lds[256];
    int b = blockIdx.x, t = threadIdx.x;
    int base = b * 1024 + t * 4;
    int v[4]; int s = 0;
#pragma unroll
    for (int j = 0; j < 4; j++) { int i = base + j; v[j] = (i < n) ? deg[i] : 0; s += v[j]; }
    lds[t] = s; __syncthreads();
    for (int st = 1; st < 256; st <<= 1) {
        int x = 0;
        if (t >= st) x = lds[t - st];
        __syncthreads();
        if (t >= st) lds[t] += x;
        __syncthreads();
    }
    int excl = (t == 0) ? 0 : lds[t - 1];
    excl += bsums[b];
    int run = excl;
#pragma unroll
    for (int j = 0; j < 4; j++) {
        int i = base + j;
        if (i < n) { row_ptr[i] = run; cursor[i] = run; run += v[j]; }
    }
}

__global__ void fill_csr(const int* __restrict__ ei, int* __restrict__ cursor,
                         int* __restrict__ col_src, int E) {
    int e = blockIdx.x * 256 + threadIdx.x;
    if (e < E) {
        int s = ei[e], d = ei[E + e];
        int p = atomicAdd(&cursor[d], 1);
        col_src[p] = s;
    }
}

// ---------------- A-panel pack: fp32 [M x Kpitch] -> bf16 hi/lo MFMA fragments ------
// Layout: slot(tile rt, kt, plane) = ((rt*NKT + kt)*2 + plane) * 512 ushorts,
// within slot: lane*8 elems; lane -> row = rt*16 + (lane&15), k = kt*32 + (lane>>4)*8 + j
__global__ void pack_a(const float* __restrict__ A, unsigned short* __restrict__ apk,
                       int Kpitch, int kbase, int NKT) {
    int g = blockIdx.x * 256 + threadIdx.x;
    int lane = g & 63;
    int t2 = g >> 6;
    int kt = t2 % NKT;
    int rt = t2 / NKT;                 // grid sized so rt < 6250 exactly
    int row = rt * 16 + (lane & 15);
    int k0 = kbase + kt * 32 + (lane >> 4) * 8;
    const float* src = A + (size_t)row * Kpitch + k0;
    float4 v0 = *(const float4*)src;
    float4 v1 = *(const float4*)(src + 4);
    float v[8] = {v0.x, v0.y, v0.z, v0.w, v1.x, v1.y, v1.z, v1.w};
    unsigned short h[8], l[8];
#pragma unroll
    for (int j = 0; j < 8; j++) {
        h[j] = bf16rn(v[j]);
        l[j] = bf16rn(v[j] - bf16tof(h[j]));
    }
    size_t slot = ((size_t)(rt * NKT + kt) * 2) * 512 + lane * 8;
    int4 vhi = make_int4((unsigned)h[0] | ((unsigned)h[1] << 16), (unsigned)h[2] | ((unsigned)h[3] << 16),
                         (unsigned)h[4] | ((unsigned)h[5] << 16), (unsigned)h[6] | ((unsigned)h[7] << 16));
    int4 vlo = make_int4((unsigned)l[0] | ((unsigned)l[1] << 16), (unsigned)l[2] | ((unsigned)l[3] << 16),
                         (unsigned)l[4] | ((unsigned)l[5] << 16), (unsigned)l[6] | ((unsigned)l[7] << 16));
    *(int4*)(apk + slot) = vhi;
    *(int4*)(apk + slot + 512) = vlo;
}

// ---------------- B pack: all weight matrices at once ------------------------------
// B[k][col] row-major, 128 cols. slot((ct*NKT+kt)*2+plane)*512 + lane*8;
// lane -> col = ct*16 + (lane&15), k = kt*32 + (lane>>4)*8 + j
__global__ void pack_b_all(const float* __restrict__ W0, const float* __restrict__ Wr,
                           const float* __restrict__ Gw1,
                           unsigned short* __restrict__ b0a, unsigned short* __restrict__ b0b,
                           unsigned short* __restrict__ b1, unsigned short* __restrict__ b2,
                           unsigned short* __restrict__ bg) {
    int bid = blockIdx.x;
    const float* src; unsigned short* dst; int kbase; int NKT; int lb;
    if (bid < 16)      { src = W0;            dst = b0a; kbase = 0;   NKT = 8; lb = bid; }
    else if (bid < 32) { src = W0;            dst = b0b; kbase = 256; NKT = 8; lb = bid - 16; }
    else if (bid < 40) { src = Wr;            dst = b1;  kbase = 0;   NKT = 4; lb = bid - 32; }
    else if (bid < 48) { src = Wr + 128*128;  dst = b2;  kbase = 0;   NKT = 4; lb = bid - 40; }
    else               { src = Gw1;           dst = bg;  kbase = 0;   NKT = 4; lb = bid - 48; }
    int g = lb * 256 + threadIdx.x;
    int lane = g & 63;
    int t2 = g >> 6;
    int kt = t2 % NKT;
    int ct = t2 / NKT;                 // 0..7
    int col = ct * 16 + (lane & 15);
    int k0 = kbase + kt * 32 + (lane >> 4) * 8;
    unsigned short h[8], l[8];
#pragma unroll
    for (int j = 0; j < 8; j++) {
        float v = src[(size_t)(k0 + j) * 128 + col];
        h[j] = bf16rn(v);
        l[j] = bf16rn(v - bf16tof(h[j]));
    }
    size_t slot = ((size_t)(ct * NKT + kt) * 2) * 512 + lane * 8;
    int4 vhi = make_int4((unsigned)h[0] | ((unsigned)h[1] << 16), (unsigned)h[2] | ((unsigned)h[3] << 16),
                         (unsigned)h[4] | ((unsigned)h[5] << 16), (unsigned)h[6] | ((unsigned)h[7] << 16));
    int4 vlo = make_int4((unsigned)l[0] | ((unsigned)l[1] << 16), (unsigned)l[2] | ((unsigned)l[3] << 16),
                         (unsigned)l[4] | ((unsigned)l[5] << 16), (unsigned)l[6] | ((unsigned)l[7] << 16));
    *(int4*)(dst + slot) = vhi;
    *(int4*)(dst + slot + 512) = vlo;
}

// ---------------- MFMA GEMM: C[M,128] = unpack(apk) @ unpack(bpk), bf16x3 ----------
// No LDS, no barriers: all fragments loaded directly from packed global layout.
// 256 thr = 4 waves in 2x2 over a 128x128 tile; wave = 64x64 (4x4 fragments 16x16).
__global__ __launch_bounds__(256) void gemm_mfma(const unsigned short* __restrict__ apk,
                                                 const unsigned short* __restrict__ bpk,
                                                 float* __restrict__ C, int M, int NKT,
                                                 int accum, const float* __restrict__ bias,
                                                 int do_relu) {
    int tid = threadIdx.x;
    int w = tid >> 6, lane = tid & 63;
    int rt0 = blockIdx.x * 8 + (w >> 1) * 4;
    int ct0 = (w & 1) * 4;
    int laneoff = lane * 8;
    f32x4 acc[4][4];
#pragma unroll
    for (int i = 0; i < 4; i++)
#pragma unroll
        for (int j = 0; j < 4; j++) acc[i][j] = (f32x4){0.f, 0.f, 0.f, 0.f};

    for (int kt = 0; kt < NKT; ++kt) {
        bf16x8 Ah[4], Al[4], Bh[4], Bl[4];
#pragma unroll
        for (int f = 0; f < 4; f++) {
            size_t ao = ((size_t)((rt0 + f) * NKT + kt) * 2) * 512 + laneoff;
            Ah[f] = *(const bf16x8*)(apk + ao);
            Al[f] = *(const bf16x8*)(apk + ao + 512);
            size_t bo = ((size_t)((ct0 + f) * NKT + kt) * 2) * 512 + laneoff;
            Bh[f] = *(const bf16x8*)(bpk + bo);
            Bl[f] = *(const bf16x8*)(bpk + bo + 512);
        }
#pragma unroll
        for (int i = 0; i < 4; i++)
#pragma unroll
            for (int j = 0; j < 4; j++) {
                acc[i][j] = __builtin_amdgcn_mfma_f32_16x16x32_bf16(Ah[i], Bh[j], acc[i][j], 0, 0, 0);
                acc[i][j] = __builtin_amdgcn_mfma_f32_16x16x32_bf16(Ah[i], Bl[j], acc[i][j], 0, 0, 0);
                acc[i][j] = __builtin_amdgcn_mfma_f32_16x16x32_bf16(Al[i], Bh[j], acc[i][j], 0, 0, 0);
            }
    }
    // epilogue: D lane map: col = lane&15, row = (lane>>4)*4 + reg
    int cbase = ct0 * 16 + (lane & 15);
    int rgrp = (lane >> 4) * 4;
#pragma unroll
    for (int i = 0; i < 4; i++) {
        int rbase = (rt0 + i) * 16 + rgrp;
#pragma unroll
        for (int j = 0; j < 4; j++) {
            int col = cbase + j * 16;
#pragma unroll
            for (int r = 0; r < 4; r++) {
                int row = rbase + r;
                if (row < M) {
                    float v = acc[i][j][r];
                    if (accum) v += C[(size_t)row * 128 + col];
                    if (bias) v += bias[col];
                    if (do_relu) v = fmaxf(v, 0.f);
                    C[(size_t)row * 128 + col] = v;
                }
            }
        }
    }
}

// ---------------- per-node attention dots ----------------
__global__ void att_dots(const float* __restrict__ h, const float* __restrict__ ws_,
                         const float* __restrict__ wd_, float* __restrict__ a_s,
                         float* __restrict__ a_d, int n) {
    int v = blockIdx.x * 4 + (threadIdx.x >> 6);
    int lane = threadIdx.x & 63;
    if (v >= n) return;
    float2 hx = ((const float2*)(h + (size_t)v * 128))[lane];
    float2 ws = ((const float2*)ws_)[lane];
    float2 wd = ((const float2*)wd_)[lane];
    float ps = hx.x * ws.x + hx.y * ws.y;
    float pd = hx.x * wd.x + hx.y * wd.y;
#pragma unroll
    for (int off = 32; off; off >>= 1) {
        ps += __shfl_xor(ps, off);
        pd += __shfl_xor(pd, off);
    }
    if (lane == 0) { a_s[v] = ps; a_d[v] = pd; }
}

// ---------------- per-node edge softmax (incl. self loop), CSR gather -------------
__global__ void edge_softmax(const int* __restrict__ row_ptr, const int* __restrict__ col_src,
                             const float* __restrict__ a_s, const float* __restrict__ a_d,
                             float* __restrict__ coef, float* __restrict__ coef_self, int n) {
    int v = blockIdx.x * 4 + (threadIdx.x >> 6);
    int lane = threadIdx.x & 63;
    if (v >= n) return;
    int s0 = row_ptr[v], s1 = row_ptr[v + 1];
    float adv = a_d[v];
    float es = lrelu(a_s[v] + adv);
    float mx = es;
    for (int k = s0 + lane; k < s1; k += 64) {
        float e = lrelu(a_s[col_src[k]] + adv);
        coef[k] = e;
        mx = fmaxf(mx, e);
    }
#pragma unroll
    for (int off = 32; off; off >>= 1) mx = fmaxf(mx, __shfl_xor(mx, off));
    float sum = 0.f;
    for (int k = s0 + lane; k < s1; k += 64) {
        float ex = expf(coef[k] - mx);
        coef[k] = ex;
        sum += ex;
    }
    if (lane == 0) sum += expf(es - mx);
#pragma unroll
    for (int off = 32; off; off >>= 1) sum += __shfl_xor(sum, off);
    float inv = 1.f / sum;
    for (int k = s0 + lane; k < s1; k += 64) coef[k] *= inv;
    if (lane == 0) coef_self[v] = expf(es - mx) * inv;
}

// ---------------- aggregation ----------------
__global__ void aggregate(const int* __restrict__ row_ptr, const int* __restrict__ col_src,
                          const float* __restrict__ coef, const float* __restrict__ coef_self,
                          const float* __restrict__ h, const float* __restrict__ bias,
                          float* __restrict__ out, int n) {
    int v = blockIdx.x * 4 + (threadIdx.x >> 6);
    int lane = threadIdx.x & 63;
    if (v >= n) return;
    int s0 = row_ptr[v], s1 = row_ptr[v + 1];
    const float2* h2 = (const float2*)h;
    float cs = coef_self[v];
    float2 hv = h2[(size_t)v * 64 + lane];
    float ax = cs * hv.x, ay = cs * hv.y;
    for (int k = s0; k < s1; k++) {
        int s = col_src[k];
        float c = coef[k];
        float2 hs = h2[(size_t)s * 64 + lane];
        ax += c * hs.x;
        ay += c * hs.y;
    }
    float2 b = ((const float2*)bias)[lane];
    float2 o; o.x = ax + b.x; o.y = ay + b.y;
    ((float2*)out)[(size_t)v * 64 + lane] = o;
}

// ---------------- batchnorm ----------------
__global__ void bn_stats(const float* __restrict__ x, double* __restrict__ sums, int n) {
    int col = threadIdx.x & 127;
    int half = threadIdx.x >> 7;
    double s = 0.0, q = 0.0;
    for (int r = blockIdx.x * 2 + half; r < n; r += gridDim.x * 2) {
        float v = x[(size_t)r * 128 + col];
        s += v;
        q += (double)v * (double)v;
    }
    __shared__ double ls[256], lq[256];
    ls[threadIdx.x] = s; lq[threadIdx.x] = q;
    __syncthreads();
    if (half == 0) {
        s += ls[threadIdx.x + 128];
        q += lq[threadIdx.x + 128];
        atomicAdd(&sums[col], s);
        atomicAdd(&sums[128 + col], q);
    }
}

__global__ void bn_finalize(const double* __restrict__ sums, const float* __restrict__ gamma,
                            const float* __restrict__ beta, float* __restrict__ coefs, int n) {
    int c = threadIdx.x;
    if (c < 128) {
        double mu = sums[c] / n;
        double var = sums[128 + c] / n - mu * mu;
        double rs = 1.0 / sqrt(var + (double)kEPS);
        float sc = (float)rs * gamma[c];
        coefs[c] = sc;
        coefs[128 + c] = beta[c] - (float)(mu * rs) * gamma[c];
    }
}

// bn + relu, emitting packed bf16 hi/lo A-fragments for the next GEMM
// (fp32 output only written when xout != nullptr, i.e. the final layer)
__global__ void bn_apply_pack(const float* __restrict__ xin, const float* __restrict__ coefs,
                              unsigned short* __restrict__ apk, float* __restrict__ xout, int n) {
    int idx = blockIdx.x * 256 + threadIdx.x;   // float4 index
    if (idx >= n * 32) return;
    float4 v = ((const float4*)xin)[idx];
    int c4 = idx & 31;
    int r = idx >> 5;
    int c = c4 * 4;
    v.x = fmaxf(v.x * coefs[c + 0] + coefs[128 + c + 0], 0.f);
    v.y = fmaxf(v.y * coefs[c + 1] + coefs[128 + c + 1], 0.f);
    v.z = fmaxf(v.z * coefs[c + 2] + coefs[128 + c + 2], 0.f);
    v.w = fmaxf(v.w * coefs[c + 3] + coefs[128 + c + 3], 0.f);
    if (xout) ((float4*)xout)[idx] = v;
    // pack into fragment layout (NKT = 4)
    int rt = r >> 4;
    int kt = c >> 5;
    int lane = (r & 15) + (((c >> 3) & 3) << 4);
    int half = c4 & 1;
    size_t slot = ((size_t)(rt * 4 + kt) * 2) * 512 + lane * 8 + half * 4;
    float vv[4] = {v.x, v.y, v.z, v.w};
    unsigned short h[4], l[4];
#pragma unroll
    for (int j = 0; j < 4; j++) {
        h[j] = bf16rn(vv[j]);
        l[j] = bf16rn(vv[j] - bf16tof(h[j]));
    }
    int2 vhi = make_int2((unsigned)h[0] | ((unsigned)h[1] << 16), (unsigned)h[2] | ((unsigned)h[3] << 16));
    int2 vlo = make_int2((unsigned)l[0] | ((unsigned)l[1] << 16), (unsigned)l[2] | ((unsigned)l[3] << 16));
    *(int2*)(apk + slot) = vhi;
    *(int2*)(apk + slot + 512) = vlo;
}

// ---------------- gate scalar ----------------
__global__ void gate_dot(const float* __restrict__ hidden, const float* __restrict__ gw2,
                         const float* __restrict__ gb2, float* __restrict__ gate, int n) {
    int v = blockIdx.x * 4 + (threadIdx.x >> 6);
    int lane = threadIdx.x & 63;
    if (v >= n) return;
    float2 hx = ((const float2*)(hidden + (size_t)v * 128))[lane];
    float2 w = ((const float2*)gw2)[lane];
    float p = hx.x * w.x + hx.y * w.y;
#pragma unroll
    for (int off = 32; off; off >>= 1) p += __shfl_xor(p, off);
    if (lane == 0) gate[v] = p + gb2[0];
}

// ---------------- graph boundaries ----------------
__global__ void graph_bounds(const int* __restrict__ batch, int* __restrict__ gstart, int n, int g) {
    int i = blockIdx.x * 256 + threadIdx.x;
    if (i > g) return;
    int lo = 0, hi = n;
    while (lo < hi) {
        int mid = (lo + hi) >> 1;
        if (batch[mid] < i) lo = mid + 1; else hi = mid;
    }
    gstart[i] = lo;
}

// ---------------- softmax-gated pooling ----------------
__global__ __launch_bounds__(512) void pool(const float* __restrict__ x, const float* __restrict__ gate,
                                            const int* __restrict__ gstart, float* __restrict__ pooled) {
    int g = blockIdx.x;
    int t = threadIdx.x;
    int col = t & 127;
    int q = t >> 7;
    int s0 = gstart[g], s1 = gstart[g + 1];
    __shared__ float red[8];
    __shared__ float acc_lds[512];
    float mx = -INFINITY;
    for (int v = s0 + t; v < s1; v += 512) mx = fmaxf(mx, gate[v]);
#pragma unroll
    for (int off = 32; off; off >>= 1) mx = fmaxf(mx, __shfl_xor(mx, off));
    if ((t & 63) == 0) red[t >> 6] = mx;
    __syncthreads();
    mx = fmaxf(fmaxf(fmaxf(red[0], red[1]), fmaxf(red[2], red[3])),
               fmaxf(fmaxf(red[4], red[5]), fmaxf(red[6], red[7])));
    __syncthreads();
    float sum = 0.f;
    for (int v = s0 + t; v < s1; v += 512) sum += expf(gate[v] - mx);
#pragma unroll
    for (int off = 32; off; off >>= 1) sum += __shfl_xor(sum, off);
    if ((t & 63) == 0) red[t >> 6] = sum;
    __syncthreads();
    sum = red[0] + red[1] + red[2] + red[3] + red[4] + red[5] + red[6] + red[7];
    if (sum == 0.f) sum = 1.f;
    float inv = 1.f / sum;
    float acc = 0.f;
    for (int v = s0 + q; v < s1; v += 4) {
        float c = expf(gate[v] - mx) * inv;
        acc += x[(size_t)v * 128 + col] * c;
    }
    acc_lds[t] = acc;
    __syncthreads();
    if (q == 0)
        pooled[(size_t)g * 128 + col] = acc_lds[col] + acc_lds[128 + col] +
                                        acc_lds[256 + col] + acc_lds[384 + col];
}

// ---------------- classifier + log_softmax ----------------
__global__ void classify(const float* __restrict__ pooled, const float* __restrict__ cls_w,
                         const float* __restrict__ cls_b, float* __restrict__ out, int g_) {
    int g = blockIdx.x * 4 + (threadIdx.x >> 6);
    int lane = threadIdx.x & 63;
    if (g >= g_) return;
    float2 p = ((const float2*)(pooled + (size_t)g * 128))[lane];
    float4 w = ((const float4*)cls_w)[lane];
    float l0 = p.x * w.x + p.y * w.z;
    float l1 = p.x * w.y + p.y * w.w;
#pragma unroll
    for (int off = 32; off; off >>= 1) {
        l0 += __shfl_xor(l0, off);
        l1 += __shfl_xor(l1, off);
    }
    if (lane == 0) {
        l0 += cls_b[0]; l1 += cls_b[1];
        float m = fmaxf(l0, l1);
        float lse = m + logf(expf(l0 - m) + expf(l1 - m));
        out[g * 2 + 0] = l0 - lse;
        out[g * 2 + 1] = l1 - lse;
    }
}

extern "C" void kernel_launch(void* const* d_in, const int* in_sizes, int n_in,
                              void* d_out, int out_size, void* d_ws, size_t ws_size,
                              hipStream_t stream) {
    const float* x        = (const float*)d_in[0];
    const int*   ei       = (const int*)d_in[1];
    const int*   batch    = (const int*)d_in[3];
    const float* W0       = (const float*)d_in[5];
    const float* W_rest   = (const float*)d_in[6];
    const float* att_src  = (const float*)d_in[7];
    const float* att_dst  = (const float*)d_in[8];
    const float* bias     = (const float*)d_in[9];
    const float* gamma    = (const float*)d_in[10];
    const float* beta     = (const float*)d_in[11];
    const float* gate_w1  = (const float*)d_in[12];
    const float* gate_b1  = (const float*)d_in[13];
    const float* gate_w2  = (const float*)d_in[14];
    const float* gate_b2  = (const float*)d_in[15];
    const float* cls_w    = (const float*)d_in[16];
    const float* cls_b    = (const float*)d_in[17];
    float* out = (float*)d_out;

    char* ws = (char*)d_ws;
    size_t off = 0;
    auto take = [&](size_t bytes) -> void* {
        void* p = ws + off;
        off += (bytes + 255) & ~(size_t)255;
        return p;
    };
    const int NRT = 6256;  // row tiles incl. padding to cover 782*8 (6250 real)
    float* h         = (float*)take((size_t)kN * kH * 4);
    float* xa        = (float*)take((size_t)kN * kH * 4);
    unsigned short* apk = (unsigned short*)take((size_t)NRT * 8 * 2 * 512 * 2); // 102.5 MB, reused
    unsigned short* bpk0a = (unsigned short*)take(8 * 8 * 2 * 512 * 2);
    unsigned short* bpk0b = (unsigned short*)take(8 * 8 * 2 * 512 * 2);
    unsigned short* bpk1  = (unsigned short*)take(8 * 4 * 2 * 512 * 2);
    unsigned short* bpk2  = (unsigned short*)take(8 * 4 * 2 * 512 * 2);
    unsigned short* bpkg  = (unsigned short*)take(8 * 4 * 2 * 512 * 2);
    float* a_s       = (float*)take((size_t)kN * 4);
    float* a_d       = (float*)take((size_t)kN * 4);
    float* coef_self = (float*)take((size_t)kN * 4);
    int*   deg       = (int*)take((size_t)kN * 4);
    int*   cursor    = (int*)take((size_t)kN * 4);
    int*   row_ptr   = (int*)take((size_t)(kN + 1) * 4);
    int*   col_src   = (int*)take((size_t)kE * 4);
    float* coef_csr  = (float*)take((size_t)kE * 4);
    int*   bsums     = (int*)take(1024 * 4);
    double* bn_sums  = (double*)take(256 * 8);
    float* bn_coefs  = (float*)take(256 * 4);
    float* gate      = (float*)take((size_t)kN * 4);
    int*   gstart    = (int*)take((size_t)(kG + 1) * 4);
    float* pooled    = (float*)take((size_t)kG * kH * 4);
    (void)ws_size; (void)in_sizes; (void)n_in; (void)out_size;

    const int NB = (kN + 1023) / 1024;
    const int GEMM_BLKS = (kN + 127) / 128;   // 782

    // ---- CSR build ----
    hipMemsetAsync(deg, 0, (size_t)kN * 4, stream);
    count_deg<<<(kE + 255) / 256, 256, 0, stream>>>(ei, deg, kE);
    scan1<<<NB, 256, 0, stream>>>(deg, bsums, kN);
    scan2<<<1, 128, 0, stream>>>(bsums, NB, row_ptr + kN);
    scan3<<<NB, 256, 0, stream>>>(deg, bsums, row_ptr, cursor, kN);
    fill_csr<<<(kE + 255) / 256, 256, 0, stream>>>(ei, cursor, col_src, kE);

    // ---- weight packing (once per call) ----
    pack_b_all<<<56, 256, 0, stream>>>(W0, W_rest, gate_w1, bpk0a, bpk0b, bpk1, bpk2, bpkg);

    // ---- layer 0: K=512 in two packed halves with C-accumulate ----
    pack_a<<<6250 * 8 / 4, 256, 0, stream>>>(x, apk, kNW, 0, 8);
    gemm_mfma<<<GEMM_BLKS, 256, 0, stream>>>(apk, bpk0a, h, kN, 8, 0, nullptr, 0);
    pack_a<<<6250 * 8 / 4, 256, 0, stream>>>(x, apk, kNW, 256, 8);
    gemm_mfma<<<GEMM_BLKS, 256, 0, stream>>>(apk, bpk0b, h, kN, 8, 1, nullptr, 0);

    // ---- 3 GAT layers ----
    for (int l = 0; l < kL; l++) {
        if (l > 0) {
            const unsigned short* bp = (l == 1) ? bpk1 : bpk2;
            gemm_mfma<<<GEMM_BLKS, 256, 0, stream>>>(apk, bp, h, kN, 4, 0, nullptr, 0);
        }
        att_dots<<<(kN + 3) / 4, 256, 0, stream>>>(h, att_src + (size_t)l * kH,
                                                   att_dst + (size_t)l * kH, a_s, a_d, kN);
        edge_softmax<<<(kN + 3) / 4, 256, 0, stream>>>(row_ptr, col_src, a_s, a_d,
                                                       coef_csr, coef_self, kN);
        aggregate<<<(kN + 3) / 4, 256, 0, stream>>>(row_ptr, col_src, coef_csr, coef_self,
                                                    h, bias + (size_t)l * kH, xa, kN);
        hipMemsetAsync(bn_sums, 0, 256 * 8, stream);
        bn_stats<<<1024, 256, 0, stream>>>(xa, bn_sums, kN);
        bn_finalize<<<1, 128, 0, stream>>>(bn_sums, gamma + (size_t)l * kH,
                                           beta + (size_t)l * kH, bn_coefs, kN);
        // packed output feeds next GEMM (or gate GEMM); fp32 only needed after last layer
        bn_apply_pack<<<((kN * 32) + 255) / 256, 256, 0, stream>>>(
            xa, bn_coefs, apk, (l == kL - 1) ? xa : nullptr, kN);
    }

    // ---- gate MLP ----
    gemm_mfma<<<GEMM_BLKS, 256, 0, stream>>>(apk, bpkg, h, kN, 4, 0, gate_b1, 1);
    gate_dot<<<(kN + 3) / 4, 256, 0, stream>>>(h, gate_w2, gate_b2, gate, kN);

    // ---- pooling + classifier ----
    graph_bounds<<<2, 256, 0, stream>>>(batch, gstart, kN, kG);
    pool<<<kG, 512, 0, stream>>>(xa, gate, gstart, pooled);
    classify<<<(kG + 3) / 4, 256, 0, stream>>>(pooled, cls_w, cls_b, out, kG);
}

// Round 10
// 1382.035 us; speedup vs baseline: 1.2339x; 1.1672x over previous
//
#include <hip/hip_runtime.h>

// Problem constants (from reference)
#define kN  100000
#define kE  1600000
#define kNW 512
#define kH  128
#define kL  3
#define kG  256
#define kNEG 0.2f
#define kEPS 1e-5f

typedef __attribute__((ext_vector_type(8))) short bf16x8;
typedef __attribute__((ext_vector_type(4))) float f32x4;

static __device__ __forceinline__ float lrelu(float v) { return v >= 0.f ? v : kNEG * v; }

static __device__ __forceinline__ unsigned short bf16rn(float x) {
    unsigned u = __float_as_uint(x);
    return (unsigned short)((u + 0x7FFFu + ((u >> 16) & 1u)) >> 16);
}
static __device__ __forceinline__ float bf16tof(unsigned short h) {
    return __uint_as_float(((unsigned)h) << 16);
}

// ---------------- CSR build ----------------
__global__ void count_deg(const int* __restrict__ ei, int* __restrict__ deg, int E) {
    int e = blockIdx.x * 256 + threadIdx.x;
    if (e < E) atomicAdd(&deg[ei[E + e]], 1);
}

__global__ void scan1(const int* __restrict__ deg, int* __restrict__ bsums, int n) {
    __shared__ int sdata[256];
    int b = blockIdx.x, t = threadIdx.x;
    int base = b * 1024 + t * 4;
    int s = 0;
#pragma unroll
    for (int j = 0; j < 4; j++) { int i = base + j; s += (i < n) ? deg[i] : 0; }
    sdata[t] = s; __syncthreads();
    for (int st = 128; st > 0; st >>= 1) { if (t < st) sdata[t] += sdata[t + st]; __syncthreads(); }
    if (t == 0) bsums[b] = sdata[0];
}

__global__ void scan2(int* __restrict__ bsums, int nb, int* __restrict__ row_ptr_last) {
    __shared__ int lds[128];
    int t = threadIdx.x;
    int v = (t < nb) ? bsums[t] : 0;
    lds[t] = v; __syncthreads();
    for (int st = 1; st < 128; st <<= 1) {
        int x = 0;
        if (t >= st) x = lds[t - st];
        __syncthreads();
        if (t >= st) lds[t] += x;
        __syncthreads();
    }
    if (t < nb) bsums[t] = lds[t] - v;
    if (t == nb - 1) row_ptr_last[0] = lds[t];
}

__global__ void scan3(const int* __restrict__ deg, const int* __restrict__ bsums,
                      int* __restrict__ row_ptr, int* __restrict__ cursor, int n) {
    __shared__ int lds[256];
    int b = blockIdx.x, t = threadIdx.x;
    int base = b * 1024 + t * 4;
    int v[4]; int s = 0;
#pragma unroll
    for (int j = 0; j < 4; j++) { int i = base + j; v[j] = (i < n) ? deg[i] : 0; s += v[j]; }
    lds[t] = s; __syncthreads();
    for (int st = 1; st < 256; st <<= 1) {
        int x = 0;
        if (t >= st) x = lds[t - st];
        __syncthreads();
        if (t >= st) lds[t] += x;
        __syncthreads();
    }
    int excl = (t == 0) ? 0 : lds[t - 1];
    excl += bsums[b];
    int run = excl;
#pragma unroll
    for (int j = 0; j < 4; j++) {
        int i = base + j;
        if (i < n) { row_ptr[i] = run; cursor[i] = run; run += v[j]; }
    }
}

__global__ void fill_csr(const int* __restrict__ ei, int* __restrict__ cursor,
                         int* __restrict__ col_src, int E) {
    int e = blockIdx.x * 256 + threadIdx.x;
    if (e < E) {
        int s = ei[e], d = ei[E + e];
        int p = atomicAdd(&cursor[d], 1);
        col_src[p] = s;
    }
}

// ---------------- B pack: weight matrices -> bf16 hi/lo MFMA fragments -------------
__global__ void pack_b_all(const float* __restrict__ W0, const float* __restrict__ Wr,
                           const float* __restrict__ Gw1,
                           unsigned short* __restrict__ b0, unsigned short* __restrict__ b1,
                           unsigned short* __restrict__ b2, unsigned short* __restrict__ bg) {
    int bid = blockIdx.x;
    const float* src; unsigned short* dst; int NKT; int lb;
    if (bid < 32)      { src = W0;            dst = b0; NKT = 16; lb = bid; }
    else if (bid < 40) { src = Wr;            dst = b1; NKT = 4;  lb = bid - 32; }
    else if (bid < 48) { src = Wr + 128*128;  dst = b2; NKT = 4;  lb = bid - 40; }
    else               { src = Gw1;           dst = bg; NKT = 4;  lb = bid - 48; }
    int g = lb * 256 + threadIdx.x;
    int lane = g & 63;
    int t2 = g >> 6;
    int kt = t2 % NKT;
    int ct = t2 / NKT;                 // 0..7
    int col = ct * 16 + (lane & 15);
    int k0 = kt * 32 + (lane >> 4) * 8;
    unsigned short h[8], l[8];
#pragma unroll
    for (int j = 0; j < 8; j++) {
        float v = src[(size_t)(k0 + j) * 128 + col];
        h[j] = bf16rn(v);
        l[j] = bf16rn(v - bf16tof(h[j]));
    }
    size_t slot = ((size_t)(ct * NKT + kt) * 2) * 512 + lane * 8;
    int4 vhi = make_int4((unsigned)h[0] | ((unsigned)h[1] << 16), (unsigned)h[2] | ((unsigned)h[3] << 16),
                         (unsigned)h[4] | ((unsigned)h[5] << 16), (unsigned)h[6] | ((unsigned)h[7] << 16));
    int4 vlo = make_int4((unsigned)l[0] | ((unsigned)l[1] << 16), (unsigned)l[2] | ((unsigned)l[3] << 16),
                         (unsigned)l[4] | ((unsigned)l[5] << 16), (unsigned)l[6] | ((unsigned)l[7] << 16));
    *(int4*)(dst + slot) = vhi;
    *(int4*)(dst + slot + 512) = vlo;
}

// ---------------- MFMA GEMM with on-the-fly A conversion + fused row-dot epilogue --
// C[M,128] = ABN(A)(fp32, pitch Kpitch) @ unpack(bpk), bf16x3.
// If abn != null: per-column BN+relu applied to A on load:
//   a_hat[k] = max(a[k]*abn[k] + abn[128+k], 0)    (fused bn_apply of previous layer)
// If att_s != null: a_s[row] = out_row . att_s (a_d likewise, if a_d != null).
// If C == null the output matrix is not stored (dot-only mode, e.g. gate MLP).
__global__ __launch_bounds__(256) void gemm_cvt(const float* __restrict__ A, int Kpitch, int NKT,
                                                const unsigned short* __restrict__ bpk,
                                                float* __restrict__ C, int M,
                                                const float* __restrict__ bias, int do_relu,
                                                const float* __restrict__ abn,
                                                const float* __restrict__ att_s,
                                                const float* __restrict__ att_d,
                                                float* __restrict__ a_s, float* __restrict__ a_d) {
    __shared__ float sAs[4][64], sAd[4][64];
    int tid = threadIdx.x;
    int w = tid >> 6, lane = tid & 63;
    int rt0 = blockIdx.x * 8 + (w >> 1) * 4;   // row tile (16 rows each)
    int ct0 = (w & 1) * 4;                     // col tile
    int laneoff = lane * 8;
    int ksub = (lane >> 4) * 8;
    const float* arow[4];
#pragma unroll
    for (int f = 0; f < 4; f++) {
        int row = (rt0 + f) * 16 + (lane & 15);
        if (row > M - 1) row = M - 1;          // clamp; garbage rows never written
        arow[f] = A + (size_t)row * Kpitch;
    }
    f32x4 acc[4][4];
#pragma unroll
    for (int i = 0; i < 4; i++)
#pragma unroll
        for (int j = 0; j < 4; j++) acc[i][j] = (f32x4){0.f, 0.f, 0.f, 0.f};

    for (int kt = 0; kt < NKT; ++kt) {
        int k0 = kt * 32 + ksub;
        float sc[8], sh[8];
        if (abn) {
            float4 s0 = *(const float4*)(abn + k0);
            float4 s1 = *(const float4*)(abn + k0 + 4);
            float4 t0 = *(const float4*)(abn + 128 + k0);
            float4 t1 = *(const float4*)(abn + 128 + k0 + 4);
            sc[0]=s0.x; sc[1]=s0.y; sc[2]=s0.z; sc[3]=s0.w;
            sc[4]=s1.x; sc[5]=s1.y; sc[6]=s1.z; sc[7]=s1.w;
            sh[0]=t0.x; sh[1]=t0.y; sh[2]=t0.z; sh[3]=t0.w;
            sh[4]=t1.x; sh[5]=t1.y; sh[6]=t1.z; sh[7]=t1.w;
        }
        bf16x8 Ah[4], Al[4], Bh[4], Bl[4];
#pragma unroll
        for (int f = 0; f < 4; f++) {
            float4 v0 = *(const float4*)(arow[f] + k0);
            float4 v1 = *(const float4*)(arow[f] + k0 + 4);
            float v[8] = {v0.x, v0.y, v0.z, v0.w, v1.x, v1.y, v1.z, v1.w};
#pragma unroll
            for (int j = 0; j < 8; j++) {
                float vj = v[j];
                if (abn) vj = fmaxf(vj * sc[j] + sh[j], 0.f);
                unsigned short hh = bf16rn(vj);
                Ah[f][j] = (short)hh;
                Al[f][j] = (short)bf16rn(vj - bf16tof(hh));
            }
            size_t bo = ((size_t)((ct0 + f) * NKT + kt) * 2) * 512 + laneoff;
            Bh[f] = *(const bf16x8*)(bpk + bo);
            Bl[f] = *(const bf16x8*)(bpk + bo + 512);
        }
#pragma unroll
        for (int i = 0; i < 4; i++)
#pragma unroll
            for (int j = 0; j < 4; j++) {
                acc[i][j] = __builtin_amdgcn_mfma_f32_16x16x32_bf16(Ah[i], Bh[j], acc[i][j], 0, 0, 0);
                acc[i][j] = __builtin_amdgcn_mfma_f32_16x16x32_bf16(Ah[i], Bl[j], acc[i][j], 0, 0, 0);
                acc[i][j] = __builtin_amdgcn_mfma_f32_16x16x32_bf16(Al[i], Bh[j], acc[i][j], 0, 0, 0);
            }
    }
    // epilogue: D lane map: col = lane&15, row = (lane>>4)*4 + reg
    int cbase = ct0 * 16 + (lane & 15);
    int rgrp = (lane >> 4) * 4;
    float atts[4], attd[4];
    if (att_s) {
#pragma unroll
        for (int j = 0; j < 4; j++) { atts[j] = att_s[cbase + j * 16]; attd[j] = att_d[cbase + j * 16]; }
    }
    float asp[4][4], adp[4][4];
#pragma unroll
    for (int i = 0; i < 4; i++) {
        int rbase = (rt0 + i) * 16 + rgrp;
#pragma unroll
        for (int r = 0; r < 4; r++) { asp[i][r] = 0.f; adp[i][r] = 0.f; }
#pragma unroll
        for (int j = 0; j < 4; j++) {
            int col = cbase + j * 16;
#pragma unroll
            for (int r = 0; r < 4; r++) {
                float val = acc[i][j][r];
                if (bias) val += bias[col];
                if (do_relu) val = fmaxf(val, 0.f);
                int row = rbase + r;
                if (C && row < M) C[(size_t)row * 128 + col] = val;
                if (att_s) { asp[i][r] += val * atts[j]; adp[i][r] += val * attd[j]; }
            }
        }
    }
    if (att_s) {
#pragma unroll
        for (int i = 0; i < 4; i++)
#pragma unroll
            for (int r = 0; r < 4; r++) {
                float s = asp[i][r], d = adp[i][r];
#pragma unroll
                for (int off = 1; off < 16; off <<= 1) {
                    s += __shfl_xor(s, off);
                    d += __shfl_xor(d, off);
                }
                if ((lane & 15) == 0) {
                    int rl = i * 16 + rgrp + r;   // 0..63
                    sAs[w][rl] = s; sAd[w][rl] = d;
                }
            }
        __syncthreads();
        if (tid < 128) {
            int grow = blockIdx.x * 128 + tid;
            if (grow < M) {
                int wp = (tid >> 6) * 2, rl = tid & 63;
                a_s[grow] = sAs[wp][rl] + sAs[wp + 1][rl];
                if (a_d) a_d[grow] = sAd[wp][rl] + sAd[wp + 1][rl];
            }
        }
    }
}

// ---------------- fused edge softmax + aggregation, one wave per node --------------
// out[v] = (sum_{e in N(v)} exp(e_e - mx) * h[src_e] + exp(e_self - mx) * h[v]) / den + bias
// 8-deep independent row gathers for memory-level parallelism.
static __device__ __forceinline__ void gather_chunk(const float2* __restrict__ h2, int lane,
                                                    int s_l, float ex_l, int cnt,
                                                    float& ax, float& ay) {
    for (int e0 = 0; e0 < cnt; e0 += 8) {
        int t0 = __shfl(s_l, e0 + 0); float c0 = __shfl(ex_l, e0 + 0);
        int t1 = __shfl(s_l, e0 + 1); float c1 = __shfl(ex_l, e0 + 1);
        int t2 = __shfl(s_l, e0 + 2); float c2 = __shfl(ex_l, e0 + 2);
        int t3 = __shfl(s_l, e0 + 3); float c3 = __shfl(ex_l, e0 + 3);
        int t4 = __shfl(s_l, e0 + 4); float c4 = __shfl(ex_l, e0 + 4);
        int t5 = __shfl(s_l, e0 + 5); float c5 = __shfl(ex_l, e0 + 5);
        int t6 = __shfl(s_l, e0 + 6); float c6 = __shfl(ex_l, e0 + 6);
        int t7 = __shfl(s_l, e0 + 7); float c7 = __shfl(ex_l, e0 + 7);
        float2 h0 = h2[(size_t)t0 * 64 + lane];
        float2 h1 = h2[(size_t)t1 * 64 + lane];
        float2 h2v = h2[(size_t)t2 * 64 + lane];
        float2 h3 = h2[(size_t)t3 * 64 + lane];
        float2 h4 = h2[(size_t)t4 * 64 + lane];
        float2 h5 = h2[(size_t)t5 * 64 + lane];
        float2 h6 = h2[(size_t)t6 * 64 + lane];
        float2 h7 = h2[(size_t)t7 * 64 + lane];
        ax += c0 * h0.x + c1 * h1.x + c2 * h2v.x + c3 * h3.x
            + c4 * h4.x + c5 * h5.x + c6 * h6.x + c7 * h7.x;
        ay += c0 * h0.y + c1 * h1.y + c2 * h2v.y + c3 * h3.y
            + c4 * h4.y + c5 * h5.y + c6 * h6.y + c7 * h7.y;
    }
}

__global__ __launch_bounds__(256) void gat_edge(const int* __restrict__ row_ptr,
                                                const int* __restrict__ col_src,
                                                const float* __restrict__ a_s,
                                                const float* __restrict__ a_d,
                                                const float* __restrict__ h,
                                                const float* __restrict__ bias,
                                                float* __restrict__ out, int n) {
    int v = blockIdx.x * 4 + (threadIdx.x >> 6);
    int lane = threadIdx.x & 63;
    if (v >= n) return;
    int s0 = row_ptr[v], s1 = row_ptr[v + 1];
    float adv = a_d[v];
    float e_self = lrelu(a_s[v] + adv);
    // chunk 0 cached in registers (covers deg<=64, the common case)
    int idx0 = s0 + lane;
    bool act0 = idx0 < s1;
    int sl0 = act0 ? col_src[idx0] : 0;
    float el0 = act0 ? lrelu(a_s[sl0] + adv) : -1e30f;
    float mx = fmaxf(e_self, el0);
    for (int k = s0 + 64 + lane; k < s1; k += 64)
        mx = fmaxf(mx, lrelu(a_s[col_src[k]] + adv));
#pragma unroll
    for (int off = 32; off; off >>= 1) mx = fmaxf(mx, __shfl_xor(mx, off));

    const float2* h2 = (const float2*)h;
    float ax = 0.f, ay = 0.f, den = 0.f;
    {
        float exl = act0 ? __expf(el0 - mx) : 0.f;
        den += exl;
        int cnt = s1 - s0; if (cnt > 64) cnt = 64;
        gather_chunk(h2, lane, sl0, exl, cnt, ax, ay);
    }
    for (int k0 = s0 + 64; k0 < s1; k0 += 64) {
        int idx = k0 + lane;
        bool act = idx < s1;
        int s_l = act ? col_src[idx] : 0;
        float exl = act ? __expf(lrelu(a_s[s_l] + adv) - mx) : 0.f;
        den += exl;
        int cnt = s1 - k0; if (cnt > 64) cnt = 64;
        gather_chunk(h2, lane, s_l, exl, cnt, ax, ay);
    }
#pragma unroll
    for (int off = 32; off; off >>= 1) den += __shfl_xor(den, off);
    float es = __expf(e_self - mx);
    den += es;
    float2 hv = h2[(size_t)v * 64 + lane];
    ax += es * hv.x; ay += es * hv.y;
    float inv = 1.f / den;
    float2 b = ((const float2*)bias)[lane];
    float2 o; o.x = ax * inv + b.x; o.y = ay * inv + b.y;
    ((float2*)out)[(size_t)v * 64 + lane] = o;
}

// ---------------- batchnorm stats (float4 loads, LDS tree reduce, 262K atomics) ----
__global__ __launch_bounds__(256) void bn_stats(const float* __restrict__ x,
                                                double* __restrict__ sums, int n) {
    int c4 = (threadIdx.x & 31) * 4;   // column quad
    int rg = threadIdx.x >> 5;         // row group 0..7
    double s0 = 0, s1 = 0, s2 = 0, s3 = 0, q0 = 0, q1 = 0, q2 = 0, q3 = 0;
    for (int r = blockIdx.x * 8 + rg; r < n; r += gridDim.x * 8) {
        float4 v = *(const float4*)(x + (size_t)r * 128 + c4);
        s0 += v.x; q0 += (double)v.x * v.x;
        s1 += v.y; q1 += (double)v.y * v.y;
        s2 += v.z; q2 += (double)v.z * v.z;
        s3 += v.w; q3 += (double)v.w * v.w;
    }
    __shared__ double ls[8][128], lq[8][128];
    ls[rg][c4] = s0; ls[rg][c4 + 1] = s1; ls[rg][c4 + 2] = s2; ls[rg][c4 + 3] = s3;
    lq[rg][c4] = q0; lq[rg][c4 + 1] = q1; lq[rg][c4 + 2] = q2; lq[rg][c4 + 3] = q3;
    __syncthreads();
    for (int st = 4; st > 0; st >>= 1) {
        if (rg < st) {
#pragma unroll
            for (int j = 0; j < 4; j++) {
                ls[rg][c4 + j] += ls[rg + st][c4 + j];
                lq[rg][c4 + j] += lq[rg + st][c4 + j];
            }
        }
        __syncthreads();
    }
    if (rg == 0) {
#pragma unroll
        for (int j = 0; j < 4; j++) {
            atomicAdd(&sums[c4 + j], ls[0][c4 + j]);
            atomicAdd(&sums[128 + c4 + j], lq[0][c4 + j]);
        }
    }
}

// Computes folded coefs, then re-zeroes sums for the next layer (each thread zeroes
// exactly the addresses it alone read — no cross-thread hazard).
__global__ void bn_finalize(double* __restrict__ sums, const float* __restrict__ gamma,
                            const float* __restrict__ beta, float* __restrict__ coefs, int n) {
    int c = threadIdx.x;
    if (c < 128) {
        double mu = sums[c] / n;
        double var = sums[128 + c] / n - mu * mu;
        double rs = 1.0 / sqrt(var + (double)kEPS);
        float sc = (float)rs * gamma[c];
        coefs[c] = sc;
        coefs[128 + c] = beta[c] - (float)(mu * rs) * gamma[c];
        sums[c] = 0.0;
        sums[128 + c] = 0.0;
    }
}

// ---------------- graph boundaries ----------------
__global__ void graph_bounds(const int* __restrict__ batch, int* __restrict__ gstart, int n, int g) {
    int i = blockIdx.x * 256 + threadIdx.x;
    if (i > g) return;
    int lo = 0, hi = n;
    while (lo < hi) {
        int mid = (lo + hi) >> 1;
        if (batch[mid] < i) lo = mid + 1; else hi = mid;
    }
    gstart[i] = lo;
}

// ---------------- softmax-gated pooling (applies final BN+relu on read) -----------
__global__ __launch_bounds__(512) void pool(const float* __restrict__ x, const float* __restrict__ gate,
                                            const int* __restrict__ gstart,
                                            const float* __restrict__ abn,
                                            float* __restrict__ pooled) {
    int g = blockIdx.x;
    int t = threadIdx.x;
    int col = t & 127;
    int q = t >> 7;
    int s0 = gstart[g], s1 = gstart[g + 1];
    float scale = abn[col], shift = abn[128 + col];
    __shared__ float red[8];
    __shared__ float acc_lds[512];
    float mx = -INFINITY;
    for (int v = s0 + t; v < s1; v += 512) mx = fmaxf(mx, gate[v]);
#pragma unroll
    for (int off = 32; off; off >>= 1) mx = fmaxf(mx, __shfl_xor(mx, off));
    if ((t & 63) == 0) red[t >> 6] = mx;
    __syncthreads();
    mx = fmaxf(fmaxf(fmaxf(red[0], red[1]), fmaxf(red[2], red[3])),
               fmaxf(fmaxf(red[4], red[5]), fmaxf(red[6], red[7])));
    __syncthreads();
    float sum = 0.f;
    for (int v = s0 + t; v < s1; v += 512) sum += expf(gate[v] - mx);
#pragma unroll
    for (int off = 32; off; off >>= 1) sum += __shfl_xor(sum, off);
    if ((t & 63) == 0) red[t >> 6] = sum;
    __syncthreads();
    sum = red[0] + red[1] + red[2] + red[3] + red[4] + red[5] + red[6] + red[7];
    if (sum == 0.f) sum = 1.f;
    float inv = 1.f / sum;
    float acc = 0.f;
    for (int v = s0 + q; v < s1; v += 4) {
        float c = expf(gate[v] - mx) * inv;
        float xv = fmaxf(x[(size_t)v * 128 + col] * scale + shift, 0.f);
        acc += xv * c;
    }
    acc_lds[t] = acc;
    __syncthreads();
    if (q == 0)
        pooled[(size_t)g * 128 + col] = acc_lds[col] + acc_lds[128 + col] +
                                        acc_lds[256 + col] + acc_lds[384 + col];
}

// ---------------- classifier + log_softmax ----------------
__global__ void classify(const float* __restrict__ pooled, const float* __restrict__ cls_w,
                         const float* __restrict__ cls_b, float* __restrict__ out, int g_) {
    int g = blockIdx.x * 4 + (threadIdx.x >> 6);
    int lane = threadIdx.x & 63;
    if (g >= g_) return;
    float2 p = ((const float2*)(pooled + (size_t)g * 128))[lane];
    float4 w = ((const float4*)cls_w)[lane];
    float l0 = p.x * w.x + p.y * w.z;
    float l1 = p.x * w.y + p.y * w.w;
#pragma unroll
    for (int off = 32; off; off >>= 1) {
        l0 += __shfl_xor(l0, off);
        l1 += __shfl_xor(l1, off);
    }
    if (lane == 0) {
        l0 += cls_b[0]; l1 += cls_b[1];
        float m = fmaxf(l0, l1);
        float lse = m + logf(expf(l0 - m) + expf(l1 - m));
        out[g * 2 + 0] = l0 - lse;
        out[g * 2 + 1] = l1 - lse;
    }
}

extern "C" void kernel_launch(void* const* d_in, const int* in_sizes, int n_in,
                              void* d_out, int out_size, void* d_ws, size_t ws_size,
                              hipStream_t stream) {
    const float* x        = (const float*)d_in[0];
    const int*   ei       = (const int*)d_in[1];
    const int*   batch    = (const int*)d_in[3];
    const float* W0       = (const float*)d_in[5];
    const float* W_rest   = (const float*)d_in[6];
    const float* att_src  = (const float*)d_in[7];
    const float* att_dst  = (const float*)d_in[8];
    const float* bias     = (const float*)d_in[9];
    const float* gamma    = (const float*)d_in[10];
    const float* beta     = (const float*)d_in[11];
    const float* gate_w1  = (const float*)d_in[12];
    const float* gate_b1  = (const float*)d_in[13];
    const float* gate_w2  = (const float*)d_in[14];
    const float* cls_w    = (const float*)d_in[16];
    const float* cls_b    = (const float*)d_in[17];
    float* out = (float*)d_out;

    char* ws = (char*)d_ws;
    size_t off = 0;
    auto take = [&](size_t bytes) -> void* {
        void* p = ws + off;
        off += (bytes + 255) & ~(size_t)255;
        return p;
    };
    float* h         = (float*)take((size_t)kN * kH * 4);
    float* xa        = (float*)take((size_t)kN * kH * 4);
    unsigned short* bpk0 = (unsigned short*)take(8 * 16 * 2 * 512 * 2);
    unsigned short* bpk1 = (unsigned short*)take(8 * 4 * 2 * 512 * 2);
    unsigned short* bpk2 = (unsigned short*)take(8 * 4 * 2 * 512 * 2);
    unsigned short* bpkg = (unsigned short*)take(8 * 4 * 2 * 512 * 2);
    float* a_s       = (float*)take((size_t)kN * 4);
    float* a_d       = (float*)take((size_t)kN * 4);
    int*   deg       = (int*)take((size_t)kN * 4);
    int*   cursor    = (int*)take((size_t)kN * 4);
    int*   row_ptr   = (int*)take((size_t)(kN + 1) * 4);
    int*   col_src   = (int*)take((size_t)kE * 4);
    int*   bsums     = (int*)take(1024 * 4);
    double* bn_sums  = (double*)take(256 * 8);
    float* bn_coefs  = (float*)take(256 * 4);
    float* gate      = (float*)take((size_t)kN * 4);
    int*   gstart    = (int*)take((size_t)(kG + 1) * 4);
    float* pooled    = (float*)take((size_t)kG * kH * 4);
    (void)ws_size; (void)in_sizes; (void)n_in; (void)out_size;

    const int NB = (kN + 1023) / 1024;
    const int GEMM_BLKS = (kN + 127) / 128;   // 782

    // ---- CSR build ----
    hipMemsetAsync(deg, 0, (size_t)kN * 4, stream);
    hipMemsetAsync(bn_sums, 0, 256 * 8, stream);   // once; bn_finalize re-zeroes
    count_deg<<<(kE + 255) / 256, 256, 0, stream>>>(ei, deg, kE);
    scan1<<<NB, 256, 0, stream>>>(deg, bsums, kN);
    scan2<<<1, 128, 0, stream>>>(bsums, NB, row_ptr + kN);
    scan3<<<NB, 256, 0, stream>>>(deg, bsums, row_ptr, cursor, kN);
    fill_csr<<<(kE + 255) / 256, 256, 0, stream>>>(ei, cursor, col_src, kE);

    // ---- weight packing ----
    pack_b_all<<<56, 256, 0, stream>>>(W0, W_rest, gate_w1, bpk0, bpk1, bpk2, bpkg);

    // ---- 3 GAT layers (BN of layer l-1 folded into layer l's A-load) ----
    for (int l = 0; l < kL; l++) {
        const float* Ain = (l == 0) ? x : xa;
        int Kp = (l == 0) ? kNW : kH;
        int NKT = (l == 0) ? 16 : 4;
        const unsigned short* bp = (l == 0) ? bpk0 : ((l == 1) ? bpk1 : bpk2);
        const float* abn = (l == 0) ? nullptr : bn_coefs;
        gemm_cvt<<<GEMM_BLKS, 256, 0, stream>>>(Ain, Kp, NKT, bp, h, kN, nullptr, 0, abn,
                                                att_src + (size_t)l * kH, att_dst + (size_t)l * kH,
                                                a_s, a_d);
        gat_edge<<<(kN + 3) / 4, 256, 0, stream>>>(row_ptr, col_src, a_s, a_d, h,
                                                   bias + (size_t)l * kH, xa, kN);
        bn_stats<<<1024, 256, 0, stream>>>(xa, bn_sums, kN);
        bn_finalize<<<1, 128, 0, stream>>>(bn_sums, gamma + (size_t)l * kH,
                                           beta + (size_t)l * kH, bn_coefs, kN);
        // no bn_apply: folded into the next consumer's load path
    }

    // ---- gate MLP: fully fused into GEMM epilogue (BN folded into A-load) ----
    // gate[v] = relu(bn(xa)@gw1 + gb1) . gw2   (+gb2 dropped: cancels in softmax)
    gemm_cvt<<<GEMM_BLKS, 256, 0, stream>>>(xa, kH, 4, bpkg, nullptr, kN, gate_b1, 1,
                                            bn_coefs, gate_w2, gate_w2, gate, nullptr);

    // ---- pooling (applies final BN+relu on read) + classifier ----
    graph_bounds<<<2, 256, 0, stream>>>(batch, gstart, kN, kG);
    pool<<<kG, 512, 0, stream>>>(xa, gate, gstart, bn_coefs, pooled);
    classify<<<(kG + 3) / 4, 256, 0, stream>>>(pooled, cls_w, cls_b, out, kG);
}